// Round 1
// baseline (535.760 us; speedup 1.0000x reference)
//
#include <hip/hip_runtime.h>

#define DIM 128
#define KEEP_PROB 0.8f

// ---------------------------------------------------------------------------
// Kernel A: init workspace. slots <- -1, accumulators <- 0. Grid-stride 16B.
// ---------------------------------------------------------------------------
__global__ void init_ws_kernel(int4* slots, int slot_vecs, float4* accs, int acc_vecs) {
    int stride = gridDim.x * blockDim.x;
    int t = blockIdx.x * blockDim.x + threadIdx.x;
    int4 m1 = make_int4(-1, -1, -1, -1);
    for (int i = t; i < slot_vecs; i += stride) slots[i] = m1;
    float4 z = make_float4(0.f, 0.f, 0.f, 0.f);
    for (int i = t; i < acc_vecs; i += stride) accs[i] = z;
}

// ---------------------------------------------------------------------------
// Kernel B: scatter batch indices into slot maps.
//   u_slot[user[b]] = b            (slot in [0,B))
//   i_slot[pos[b]]  = b            (slot in [0,B))
//   i_slot[neg[b]]  = B + b        (slot in [B,2B))
// Duplicate indices: last writer wins; all consumers RE-READ the slot map, so
// everyone agrees on the winning accumulator row. Correct by construction.
// ---------------------------------------------------------------------------
__global__ void slot_kernel(const int* __restrict__ user, const int* __restrict__ pos,
                            const int* __restrict__ neg, int* __restrict__ u_slot,
                            int* __restrict__ i_slot, int B) {
    int t = blockIdx.x * blockDim.x + threadIdx.x;
    if (t < B) {
        u_slot[user[t]] = t;
    } else if (t < 2 * B) {
        i_slot[pos[t - B]] = t - B;
    } else if (t < 3 * B) {
        i_slot[neg[t - 2 * B]] = (t - 2 * B) + B;
    }
}

// ---------------------------------------------------------------------------
// Kernel C: edge scatter, filtered by slot maps.
// One thread per edge for metadata; wave-cooperative (64 lanes x float2) for
// the 512B gather + atomic accumulate of each "hit" edge. Hits are rare
// (~4% user-side, ~15% item-side, x0.8 dropout), found via ballot.
// ---------------------------------------------------------------------------
__global__ void edge_kernel(const float* __restrict__ vals, const float* __restrict__ keep,
                            const int* __restrict__ rows, const int* __restrict__ cols,
                            const float* __restrict__ u0, const float* __restrict__ i0,
                            const int* __restrict__ u_slot, const int* __restrict__ i_slot,
                            float* __restrict__ u1c, float* __restrict__ i1c, int E) {
    int t = blockIdx.x * blockDim.x + threadIdx.x;
    int lane = threadIdx.x & 63;
    int base = t & ~63;
    if (base >= E) return;

    float dval = 0.f;
    int r = 0, c = 0, us = -1, is = -1;
    if (t < E) {
        float km = keep[t];
        float v  = vals[t];
        r = rows[t];
        c = cols[t];
        if (km < KEEP_PROB) dval = v * 1.25f;   // 1/0.8 == 1.25 exactly
        if (dval != 0.f) {
            us = u_slot[r];   // need this user's u1 row?
            is = i_slot[c];   // need this item's i1 row?
        }
    }

    unsigned long long umask = __ballot(us >= 0);
    unsigned long long imask = __ballot(is >= 0);
    int o = lane * 2;

    // u1[r] += dval * i0[c] for each hit lane j (wave-wide vector op)
    while (umask) {
        int j = __ffsll(umask) - 1;
        umask &= umask - 1;
        int   cj = __shfl(c, j);
        int   sj = __shfl(us, j);
        float dv = __shfl(dval, j);
        float2 src = *(const float2*)(i0 + (size_t)cj * DIM + o);
        float* dst = u1c + (size_t)sj * DIM + o;
        atomicAdd(dst,     dv * src.x);
        atomicAdd(dst + 1, dv * src.y);
    }
    // i1[c] += dval * u0[r]
    while (imask) {
        int j = __ffsll(imask) - 1;
        imask &= imask - 1;
        int   rj = __shfl(r, j);
        int   sj = __shfl(is, j);
        float dv = __shfl(dval, j);
        float2 src = *(const float2*)(u0 + (size_t)rj * DIM + o);
        float* dst = i1c + (size_t)sj * DIM + o;
        atomicAdd(dst,     dv * src.x);
        atomicAdd(dst + 1, dv * src.y);
    }
}

// ---------------------------------------------------------------------------
// Kernel D: per-batch scoring. One wave per batch element b.
//   u = 0.5*(u0[user[b]] + u1c[u_slot[user[b]]])  etc.
//   out[b] = dot(u, i_pos); out[B+b] = dot(u, i_neg)
// ---------------------------------------------------------------------------
__global__ void score_kernel(const float* __restrict__ u0, const float* __restrict__ i0,
                             const float* __restrict__ u1c, const float* __restrict__ i1c,
                             const int* __restrict__ user, const int* __restrict__ pos,
                             const int* __restrict__ neg, const int* __restrict__ u_slot,
                             const int* __restrict__ i_slot, float* __restrict__ out, int B) {
    int wave = (blockIdx.x * blockDim.x + threadIdx.x) >> 6;
    int lane = threadIdx.x & 63;
    if (wave >= B) return;

    int ub = user[wave], pb = pos[wave], nb = neg[wave];
    int usl = u_slot[ub], psl = i_slot[pb], nsl = i_slot[nb];
    int o = lane * 2;

    float2 a0 = *(const float2*)(u0  + (size_t)ub  * DIM + o);
    float2 a1 = *(const float2*)(u1c + (size_t)usl * DIM + o);
    float2 p0 = *(const float2*)(i0  + (size_t)pb  * DIM + o);
    float2 p1 = *(const float2*)(i1c + (size_t)psl * DIM + o);
    float2 n0 = *(const float2*)(i0  + (size_t)nb  * DIM + o);
    float2 n1 = *(const float2*)(i1c + (size_t)nsl * DIM + o);

    float ux = (a0.x + a1.x) * 0.5f, uy = (a0.y + a1.y) * 0.5f;
    float px = (p0.x + p1.x) * 0.5f, py = (p0.y + p1.y) * 0.5f;
    float nx = (n0.x + n1.x) * 0.5f, ny = (n0.y + n1.y) * 0.5f;

    float ps = ux * px + uy * py;
    float ns = ux * nx + uy * ny;
    for (int off = 32; off > 0; off >>= 1) {
        ps += __shfl_down(ps, off);
        ns += __shfl_down(ns, off);
    }
    if (lane == 0) {
        out[wave]     = ps;
        out[B + wave] = ns;
    }
}

extern "C" void kernel_launch(void* const* d_in, const int* in_sizes, int n_in,
                              void* d_out, int out_size, void* d_ws, size_t ws_size,
                              hipStream_t stream) {
    const float* user_emb = (const float*)d_in[0];
    const float* item_emb = (const float*)d_in[1];
    const float* vals     = (const float*)d_in[2];
    const float* keep     = (const float*)d_in[3];
    const int*   rows     = (const int*)d_in[4];
    const int*   cols     = (const int*)d_in[5];
    const int*   user     = (const int*)d_in[6];
    const int*   pos      = (const int*)d_in[7];
    const int*   neg      = (const int*)d_in[8];
    float* out = (float*)d_out;

    int U = in_sizes[0] / DIM;   // 100000
    int I = in_sizes[1] / DIM;   // 50000
    int E = in_sizes[2];         // 3200000
    int B = in_sizes[6];         // 4096

    // Workspace layout (all 16B aligned):
    //   u_slot: U ints | i_slot: I ints | u1c: B*DIM f32 | i1c: 2B*DIM f32
    char* ws = (char*)d_ws;
    int* u_slot = (int*)ws;
    int* i_slot = u_slot + U;
    size_t slot_bytes = ((size_t)(U + I) * sizeof(int) + 15) & ~(size_t)15;
    float* u1c = (float*)(ws + slot_bytes);
    float* i1c = u1c + (size_t)B * DIM;

    int slot_vecs = (int)(slot_bytes / 16);
    int acc_vecs  = (3 * B * DIM) / 4;   // u1c + i1c contiguous, in float4s

    // A: init
    init_ws_kernel<<<1024, 256, 0, stream>>>((int4*)u_slot, slot_vecs, (float4*)u1c, acc_vecs);
    // B: slot scatter
    slot_kernel<<<(3 * B + 255) / 256, 256, 0, stream>>>(user, pos, neg, u_slot, i_slot, B);
    // C: filtered edge scatter
    edge_kernel<<<(E + 255) / 256, 256, 0, stream>>>(vals, keep, rows, cols, user_emb,
                                                     item_emb, u_slot, i_slot, u1c, i1c, E);
    // D: score
    score_kernel<<<(B * 64 + 255) / 256, 256, 0, stream>>>(user_emb, item_emb, u1c, i1c,
                                                           user, pos, neg, u_slot, i_slot,
                                                           out, B);
}

// Round 2
// 322.301 us; speedup vs baseline: 1.6623x; 1.6623x over previous
//
#include <hip/hip_runtime.h>

#define DIM 128
#define KEEP_PROB 0.8f

// ---------------------------------------------------------------------------
// Workspace layout (set up in kernel_launch):
//   u_slot[U] int | i_slot[I] int | cnt[3B] | offs[3B] | cursor[3B]
//   u1c[B*DIM] f32 | i1c[2B*DIM] f32 | entries[cap] int2 {src, dval_bits}
// Dest id space: user-slot d in [0,B); item-slot d in [B,3B).
// ---------------------------------------------------------------------------

// A: slots <- -1, cnt <- 0. (Accumulators need no init: gather overwrites.)
__global__ void init_ws_kernel(int4* slots, int slot_vecs, int4* cnt, int cnt_vecs) {
    int stride = gridDim.x * blockDim.x;
    int t = blockIdx.x * blockDim.x + threadIdx.x;
    int4 m1 = make_int4(-1, -1, -1, -1);
    for (int i = t; i < slot_vecs; i += stride) slots[i] = m1;
    int4 z = make_int4(0, 0, 0, 0);
    for (int i = t; i < cnt_vecs; i += stride) cnt[i] = z;
}

// B: scatter batch indices into slot maps (dup indices: last writer wins;
// everyone re-reads the map, so all agree on the winning compact row).
__global__ void slot_kernel(const int* __restrict__ user, const int* __restrict__ pos,
                            const int* __restrict__ neg, int* __restrict__ u_slot,
                            int* __restrict__ i_slot, int B) {
    int t = blockIdx.x * blockDim.x + threadIdx.x;
    if (t < B) {
        u_slot[user[t]] = t;
    } else if (t < 2 * B) {
        i_slot[pos[t - B]] = t - B;
    } else if (t < 3 * B) {
        i_slot[neg[t - 2 * B]] = (t - 2 * B) + B;
    }
}

// C: count hits per destination. 4 edges/thread, vectorized metadata loads.
// Predicate = kept (km < 0.8) && slot >= 0  (vals not needed here; zero-val
// edges contribute 0 and are handled consistently in fill).
__global__ void count_kernel(const float* __restrict__ keep, const int* __restrict__ rows,
                             const int* __restrict__ cols, const int* __restrict__ u_slot,
                             const int* __restrict__ i_slot, int* __restrict__ cnt,
                             int E, int B) {
    int t = blockIdx.x * blockDim.x + threadIdx.x;
    int base = t * 4;
    if (base >= E) return;
    if (base + 3 < E) {
        float4 km = *(const float4*)(keep + base);
        int4 r4 = *(const int4*)(rows + base);
        int4 c4 = *(const int4*)(cols + base);
        float k[4] = {km.x, km.y, km.z, km.w};
        int rr[4] = {r4.x, r4.y, r4.z, r4.w};
        int cc[4] = {c4.x, c4.y, c4.z, c4.w};
#pragma unroll
        for (int j = 0; j < 4; j++) {
            if (k[j] < KEEP_PROB) {
                int us = u_slot[rr[j]];
                if (us >= 0) atomicAdd(&cnt[us], 1);
                int is = i_slot[cc[j]];
                if (is >= 0) atomicAdd(&cnt[B + is], 1);
            }
        }
    } else {
        for (int e = base; e < E; e++) {
            if (keep[e] < KEEP_PROB) {
                int us = u_slot[rows[e]];
                if (us >= 0) atomicAdd(&cnt[us], 1);
                int is = i_slot[cols[e]];
                if (is >= 0) atomicAdd(&cnt[B + is], 1);
            }
        }
    }
}

// D: exclusive prefix sum over cnt[n] -> offs, cursor. n = 3B = 12288.
// One block of 1024 (16 waves); wave shfl-scan + cross-wave LDS scan.
__global__ void scan_kernel(const int* __restrict__ cnt, int* __restrict__ offs,
                            int* __restrict__ cursor, int n) {
    __shared__ int wave_tot[16];
    __shared__ int carry_s;
    int tid = threadIdx.x, lane = tid & 63, wv = tid >> 6;
    if (tid == 0) carry_s = 0;
    __syncthreads();
    for (int base = 0; base < n; base += 1024) {
        int v = (base + tid < n) ? cnt[base + tid] : 0;
        int x = v;
#pragma unroll
        for (int off = 1; off < 64; off <<= 1) {
            int y = __shfl_up(x, off);
            if (lane >= off) x += y;
        }
        if (lane == 63) wave_tot[wv] = x;
        __syncthreads();
        if (wv == 0 && lane < 16) {
            int tot = wave_tot[lane];
            int s = tot;
#pragma unroll
            for (int off = 1; off < 16; off <<= 1) {
                int y = __shfl_up(s, off);
                if (lane >= off) s += y;
            }
            wave_tot[lane] = s - tot;   // exclusive prefix of wave totals
        }
        __syncthreads();
        int excl = (x - v) + wave_tot[wv] + carry_s;
        if (base + tid < n) { offs[base + tid] = excl; cursor[base + tid] = excl; }
        __syncthreads();
        if (tid == 1023) carry_s += wave_tot[15] + x;   // chunk total
        __syncthreads();
    }
}

// E: fill CSR entries. Same traversal/predicate as count.
__global__ void fill_kernel(const float* __restrict__ vals, const float* __restrict__ keep,
                            const int* __restrict__ rows, const int* __restrict__ cols,
                            const int* __restrict__ u_slot, const int* __restrict__ i_slot,
                            int* __restrict__ cursor, int2* __restrict__ entries,
                            long long cap, int E, int B) {
    int t = blockIdx.x * blockDim.x + threadIdx.x;
    int base = t * 4;
    if (base >= E) return;
    if (base + 3 < E) {
        float4 km = *(const float4*)(keep + base);
        float4 vv = *(const float4*)(vals + base);
        int4 r4 = *(const int4*)(rows + base);
        int4 c4 = *(const int4*)(cols + base);
        float k[4] = {km.x, km.y, km.z, km.w};
        float v[4] = {vv.x, vv.y, vv.z, vv.w};
        int rr[4] = {r4.x, r4.y, r4.z, r4.w};
        int cc[4] = {c4.x, c4.y, c4.z, c4.w};
#pragma unroll
        for (int j = 0; j < 4; j++) {
            if (k[j] < KEEP_PROB) {
                float dv = v[j] * 1.25f;   // 1/0.8 exactly
                int us = u_slot[rr[j]];
                if (us >= 0) {
                    int p = atomicAdd(&cursor[us], 1);
                    if (p < cap) entries[p] = make_int2(cc[j], __float_as_int(dv));
                }
                int is = i_slot[cc[j]];
                if (is >= 0) {
                    int p = atomicAdd(&cursor[B + is], 1);
                    if (p < cap) entries[p] = make_int2(rr[j], __float_as_int(dv));
                }
            }
        }
    } else {
        for (int e = base; e < E; e++) {
            if (keep[e] < KEEP_PROB) {
                float dv = vals[e] * 1.25f;
                int us = u_slot[rows[e]];
                if (us >= 0) {
                    int p = atomicAdd(&cursor[us], 1);
                    if (p < cap) entries[p] = make_int2(cols[e], __float_as_int(dv));
                }
                int is = i_slot[cols[e]];
                if (is >= 0) {
                    int p = atomicAdd(&cursor[B + is], 1);
                    if (p < cap) entries[p] = make_int2(rows[e], __float_as_int(dv));
                }
            }
        }
    }
}

// F: gather. One wave per destination row; lane owns dims {2*lane, 2*lane+1}.
// Pure loads + fmac + one plain store. No atomics.
__global__ void gather_kernel(const int2* __restrict__ entries, const int* __restrict__ offs,
                              const int* __restrict__ cnt, const float* __restrict__ u0,
                              const float* __restrict__ i0, float* __restrict__ u1c,
                              float* __restrict__ i1c, long long cap, int B) {
    int wave = (blockIdx.x * blockDim.x + threadIdx.x) >> 6;
    int lane = threadIdx.x & 63;
    if (wave >= 3 * B) return;
    const float* table;
    float* dst;
    if (wave < B) { table = i0; dst = u1c + (size_t)wave * DIM; }
    else          { table = u0; dst = i1c + (size_t)(wave - B) * DIM; }
    long long start = offs[wave];
    long long end = start + cnt[wave];
    if (end > cap) end = cap;
    int o = lane * 2;
    float ax = 0.f, ay = 0.f;
    for (long long k = start; k < end; k++) {
        int2 e = entries[k];                       // same addr all lanes: broadcast
        float dv = __int_as_float(e.y);
        float2 s = *(const float2*)(table + (size_t)e.x * DIM + o);
        ax += dv * s.x;
        ay += dv * s.y;
    }
    *(float2*)(dst + o) = make_float2(ax, ay);
}

// G: scoring. One wave per batch element.
__global__ void score_kernel(const float* __restrict__ u0, const float* __restrict__ i0,
                             const float* __restrict__ u1c, const float* __restrict__ i1c,
                             const int* __restrict__ user, const int* __restrict__ pos,
                             const int* __restrict__ neg, const int* __restrict__ u_slot,
                             const int* __restrict__ i_slot, float* __restrict__ out, int B) {
    int wave = (blockIdx.x * blockDim.x + threadIdx.x) >> 6;
    int lane = threadIdx.x & 63;
    if (wave >= B) return;

    int ub = user[wave], pb = pos[wave], nb = neg[wave];
    int usl = u_slot[ub], psl = i_slot[pb], nsl = i_slot[nb];
    int o = lane * 2;

    float2 a0 = *(const float2*)(u0  + (size_t)ub  * DIM + o);
    float2 a1 = *(const float2*)(u1c + (size_t)usl * DIM + o);
    float2 p0 = *(const float2*)(i0  + (size_t)pb  * DIM + o);
    float2 p1 = *(const float2*)(i1c + (size_t)psl * DIM + o);
    float2 n0 = *(const float2*)(i0  + (size_t)nb  * DIM + o);
    float2 n1 = *(const float2*)(i1c + (size_t)nsl * DIM + o);

    float ux = (a0.x + a1.x) * 0.5f, uy = (a0.y + a1.y) * 0.5f;
    float px = (p0.x + p1.x) * 0.5f, py = (p0.y + p1.y) * 0.5f;
    float nx = (n0.x + n1.x) * 0.5f, ny = (n0.y + n1.y) * 0.5f;

    float ps = ux * px + uy * py;
    float ns = ux * nx + uy * ny;
    for (int off = 32; off > 0; off >>= 1) {
        ps += __shfl_down(ps, off);
        ns += __shfl_down(ns, off);
    }
    if (lane == 0) {
        out[wave]     = ps;
        out[B + wave] = ns;
    }
}

extern "C" void kernel_launch(void* const* d_in, const int* in_sizes, int n_in,
                              void* d_out, int out_size, void* d_ws, size_t ws_size,
                              hipStream_t stream) {
    const float* user_emb = (const float*)d_in[0];
    const float* item_emb = (const float*)d_in[1];
    const float* vals     = (const float*)d_in[2];
    const float* keep     = (const float*)d_in[3];
    const int*   rows     = (const int*)d_in[4];
    const int*   cols     = (const int*)d_in[5];
    const int*   user     = (const int*)d_in[6];
    const int*   pos      = (const int*)d_in[7];
    const int*   neg      = (const int*)d_in[8];
    float* out = (float*)d_out;

    int U = in_sizes[0] / DIM;   // 100000
    int I = in_sizes[1] / DIM;   // 50000
    int E = in_sizes[2];         // 3200000
    int B = in_sizes[6];         // 4096

    char* p = (char*)d_ws;
    int* u_slot = (int*)p;              p += (size_t)U * 4;
    int* i_slot = (int*)p;              p += (size_t)I * 4;
    int* cnt    = (int*)p;              p += (size_t)3 * B * 4;
    int* offs   = (int*)p;              p += (size_t)3 * B * 4;
    int* cursor = (int*)p;              p += (size_t)3 * B * 4;
    float* u1c  = (float*)p;            p += (size_t)B * DIM * 4;
    float* i1c  = (float*)p;            p += (size_t)2 * B * DIM * 4;
    int2* entries = (int2*)p;
    size_t used = (size_t)(p - (char*)d_ws);
    long long cap = ((long long)ws_size - (long long)used) / (long long)sizeof(int2);
    if (cap > (2ll << 20)) cap = 2ll << 20;   // expected hits ~492k; 2M is ample
    if (cap < 0) cap = 0;

    int slot_vecs = (U + I) / 4;        // 150000/4, exact
    int cnt_vecs  = (3 * B) / 4;        // 12288/4, exact

    init_ws_kernel<<<256, 256, 0, stream>>>((int4*)u_slot, slot_vecs, (int4*)cnt, cnt_vecs);
    slot_kernel<<<(3 * B + 255) / 256, 256, 0, stream>>>(user, pos, neg, u_slot, i_slot, B);

    int scan_threads = (E + 3) / 4;
    count_kernel<<<(scan_threads + 255) / 256, 256, 0, stream>>>(keep, rows, cols, u_slot,
                                                                 i_slot, cnt, E, B);
    scan_kernel<<<1, 1024, 0, stream>>>(cnt, offs, cursor, 3 * B);
    fill_kernel<<<(scan_threads + 255) / 256, 256, 0, stream>>>(vals, keep, rows, cols,
                                                                u_slot, i_slot, cursor,
                                                                entries, cap, E, B);
    gather_kernel<<<(3 * B * 64 + 255) / 256, 256, 0, stream>>>(entries, offs, cnt, user_emb,
                                                                item_emb, u1c, i1c, cap, B);
    score_kernel<<<(B * 64 + 255) / 256, 256, 0, stream>>>(user_emb, item_emb, u1c, i1c,
                                                           user, pos, neg, u_slot, i_slot,
                                                           out, B);
}

// Round 3
// 227.876 us; speedup vs baseline: 2.3511x; 1.4144x over previous
//
#include <hip/hip_runtime.h>

#define DIM 128
#define KEEP_PROB 0.8f
#define UCAP 96    // user-side bucket capacity  (kept-degree ~Poisson(25.6), max<<96)
#define ICAP 160   // item-side bucket capacity  (kept-degree ~Poisson(51.2), max<<160)

// ---------------------------------------------------------------------------
// A: slots <- -1; cnt/offs/cursor <- 0. Grid-stride int4.
// ---------------------------------------------------------------------------
__global__ void init_ws_kernel(int4* slots, int slot_vecs, int4* ctrs, int ctr_vecs) {
    int stride = gridDim.x * blockDim.x;
    int t = blockIdx.x * blockDim.x + threadIdx.x;
    int4 m1 = make_int4(-1, -1, -1, -1);
    for (int i = t; i < slot_vecs; i += stride) slots[i] = m1;
    int4 z = make_int4(0, 0, 0, 0);
    for (int i = t; i < ctr_vecs; i += stride) ctrs[i] = z;
}

// ---------------------------------------------------------------------------
// B: scatter batch indices into slot maps (dup indices: last writer wins;
// every consumer re-reads the map, so all agree on the winning compact row).
// ---------------------------------------------------------------------------
__global__ void slot_kernel(const int* __restrict__ user, const int* __restrict__ pos,
                            const int* __restrict__ neg, int* __restrict__ u_slot,
                            int* __restrict__ i_slot, int B) {
    int t = blockIdx.x * blockDim.x + threadIdx.x;
    if (t < B) {
        u_slot[user[t]] = t;
    } else if (t < 2 * B) {
        i_slot[pos[t - B]] = t - B;
    } else if (t < 3 * B) {
        i_slot[neg[t - 2 * B]] = (t - 2 * B) + B;
    }
}

// ---------------------------------------------------------------------------
// C (bucket path): single-pass fill into fixed-stride buckets.
//   user dest d: entries[d*UCAP + p], item dest d: entries[B*UCAP + d*ICAP + p]
// cursor doubles as the per-dest count read by gather.
// ---------------------------------------------------------------------------
__global__ void fill_bucket_kernel(const float* __restrict__ vals, const float* __restrict__ keep,
                                   const int* __restrict__ rows, const int* __restrict__ cols,
                                   const int* __restrict__ u_slot, const int* __restrict__ i_slot,
                                   int* __restrict__ cursor, int2* __restrict__ entries,
                                   int E, int B) {
    int t = blockIdx.x * blockDim.x + threadIdx.x;
    int base = t * 4;
    if (base >= E) return;
    long long ibase = (long long)B * UCAP;
    if (base + 3 < E) {
        float4 km = *(const float4*)(keep + base);
        float4 vv = *(const float4*)(vals + base);
        int4 r4 = *(const int4*)(rows + base);
        int4 c4 = *(const int4*)(cols + base);
        float k[4] = {km.x, km.y, km.z, km.w};
        float v[4] = {vv.x, vv.y, vv.z, vv.w};
        int rr[4] = {r4.x, r4.y, r4.z, r4.w};
        int cc[4] = {c4.x, c4.y, c4.z, c4.w};
#pragma unroll
        for (int j = 0; j < 4; j++) {
            if (k[j] < KEEP_PROB) {
                float dv = v[j] * 1.25f;   // 1/0.8 exactly representable
                int us = u_slot[rr[j]];
                if (us >= 0) {
                    int p = atomicAdd(&cursor[us], 1);
                    if (p < UCAP) entries[(long long)us * UCAP + p] = make_int2(cc[j], __float_as_int(dv));
                }
                int is = i_slot[cc[j]];
                if (is >= 0) {
                    int p = atomicAdd(&cursor[B + is], 1);
                    if (p < ICAP) entries[ibase + (long long)is * ICAP + p] = make_int2(rr[j], __float_as_int(dv));
                }
            }
        }
    } else {
        for (int e = base; e < E; e++) {
            if (keep[e] < KEEP_PROB) {
                float dv = vals[e] * 1.25f;
                int us = u_slot[rows[e]];
                if (us >= 0) {
                    int p = atomicAdd(&cursor[us], 1);
                    if (p < UCAP) entries[(long long)us * UCAP + p] = make_int2(cols[e], __float_as_int(dv));
                }
                int is = i_slot[cols[e]];
                if (is >= 0) {
                    int p = atomicAdd(&cursor[B + is], 1);
                    if (p < ICAP) entries[ibase + (long long)is * ICAP + p] = make_int2(rows[e], __float_as_int(dv));
                }
            }
        }
    }
}

// ---------------------------------------------------------------------------
// CSR fallback path (used only if ws_size can't hold the buckets):
// count -> scan -> fill_csr, identical semantics to round 2.
// ---------------------------------------------------------------------------
__global__ void count_kernel(const float* __restrict__ keep, const int* __restrict__ rows,
                             const int* __restrict__ cols, const int* __restrict__ u_slot,
                             const int* __restrict__ i_slot, int* __restrict__ cnt,
                             int E, int B) {
    int t = blockIdx.x * blockDim.x + threadIdx.x;
    int base = t * 4;
    if (base >= E) return;
    if (base + 3 < E) {
        float4 km = *(const float4*)(keep + base);
        int4 r4 = *(const int4*)(rows + base);
        int4 c4 = *(const int4*)(cols + base);
        float k[4] = {km.x, km.y, km.z, km.w};
        int rr[4] = {r4.x, r4.y, r4.z, r4.w};
        int cc[4] = {c4.x, c4.y, c4.z, c4.w};
#pragma unroll
        for (int j = 0; j < 4; j++) {
            if (k[j] < KEEP_PROB) {
                int us = u_slot[rr[j]];
                if (us >= 0) atomicAdd(&cnt[us], 1);
                int is = i_slot[cc[j]];
                if (is >= 0) atomicAdd(&cnt[B + is], 1);
            }
        }
    } else {
        for (int e = base; e < E; e++) {
            if (keep[e] < KEEP_PROB) {
                int us = u_slot[rows[e]];
                if (us >= 0) atomicAdd(&cnt[us], 1);
                int is = i_slot[cols[e]];
                if (is >= 0) atomicAdd(&cnt[B + is], 1);
            }
        }
    }
}

__global__ void scan_kernel(const int* __restrict__ cnt, int* __restrict__ offs,
                            int* __restrict__ cursor, int n) {
    __shared__ int wave_tot[16];
    __shared__ int carry_s;
    int tid = threadIdx.x, lane = tid & 63, wv = tid >> 6;
    if (tid == 0) carry_s = 0;
    __syncthreads();
    for (int base = 0; base < n; base += 1024) {
        int v = (base + tid < n) ? cnt[base + tid] : 0;
        int x = v;
#pragma unroll
        for (int off = 1; off < 64; off <<= 1) {
            int y = __shfl_up(x, off);
            if (lane >= off) x += y;
        }
        if (lane == 63) wave_tot[wv] = x;
        __syncthreads();
        if (wv == 0 && lane < 16) {
            int tot = wave_tot[lane];
            int s = tot;
#pragma unroll
            for (int off = 1; off < 16; off <<= 1) {
                int y = __shfl_up(s, off);
                if (lane >= off) s += y;
            }
            wave_tot[lane] = s - tot;
        }
        __syncthreads();
        int excl = (x - v) + wave_tot[wv] + carry_s;
        if (base + tid < n) { offs[base + tid] = excl; cursor[base + tid] = excl; }
        __syncthreads();
        if (tid == 1023) carry_s += wave_tot[15] + x;
        __syncthreads();
    }
}

__global__ void fill_csr_kernel(const float* __restrict__ vals, const float* __restrict__ keep,
                                const int* __restrict__ rows, const int* __restrict__ cols,
                                const int* __restrict__ u_slot, const int* __restrict__ i_slot,
                                int* __restrict__ cursor, int2* __restrict__ entries,
                                long long cap, int E, int B) {
    int t = blockIdx.x * blockDim.x + threadIdx.x;
    int base = t * 4;
    if (base >= E) return;
    if (base + 3 < E) {
        float4 km = *(const float4*)(keep + base);
        float4 vv = *(const float4*)(vals + base);
        int4 r4 = *(const int4*)(rows + base);
        int4 c4 = *(const int4*)(cols + base);
        float k[4] = {km.x, km.y, km.z, km.w};
        float v[4] = {vv.x, vv.y, vv.z, vv.w};
        int rr[4] = {r4.x, r4.y, r4.z, r4.w};
        int cc[4] = {c4.x, c4.y, c4.z, c4.w};
#pragma unroll
        for (int j = 0; j < 4; j++) {
            if (k[j] < KEEP_PROB) {
                float dv = v[j] * 1.25f;
                int us = u_slot[rr[j]];
                if (us >= 0) {
                    int p = atomicAdd(&cursor[us], 1);
                    if (p < cap) entries[p] = make_int2(cc[j], __float_as_int(dv));
                }
                int is = i_slot[cc[j]];
                if (is >= 0) {
                    int p = atomicAdd(&cursor[B + is], 1);
                    if (p < cap) entries[p] = make_int2(rr[j], __float_as_int(dv));
                }
            }
        }
    } else {
        for (int e = base; e < E; e++) {
            if (keep[e] < KEEP_PROB) {
                float dv = vals[e] * 1.25f;
                int us = u_slot[rows[e]];
                if (us >= 0) {
                    int p = atomicAdd(&cursor[us], 1);
                    if (p < cap) entries[p] = make_int2(cols[e], __float_as_int(dv));
                }
                int is = i_slot[cols[e]];
                if (is >= 0) {
                    int p = atomicAdd(&cursor[B + is], 1);
                    if (p < cap) entries[p] = make_int2(rows[e], __float_as_int(dv));
                }
            }
        }
    }
}

// ---------------------------------------------------------------------------
// F: gather, one wave per destination row. Coalesced 64-entry block prefetch
// (one entry per lane), shfl-broadcast in groups of 4 -> four independent
// 512B row gathers in flight (MLP=4). No atomics, single plain store.
// mode==1: bucket layout (base computed analytically, cnt from cursor).
// mode==0: CSR layout (base from offs).
// ---------------------------------------------------------------------------
__global__ void gather_kernel(const int2* __restrict__ entries, const int* __restrict__ offs,
                              const int* __restrict__ cntp, const float* __restrict__ u0,
                              const float* __restrict__ i0, float* __restrict__ u1c,
                              float* __restrict__ i1c, int B, int mode, long long cap) {
    int wave = (blockIdx.x * blockDim.x + threadIdx.x) >> 6;
    int lane = threadIdx.x & 63;
    if (wave >= 3 * B) return;
    const float* table;
    float* dst;
    if (wave < B) { table = i0; dst = u1c + (size_t)wave * DIM; }
    else          { table = u0; dst = i1c + (size_t)(wave - B) * DIM; }

    int n = cntp[wave];
    long long base;
    if (mode == 1) {
        if (wave < B) { base = (long long)wave * UCAP; if (n > UCAP) n = UCAP; }
        else          { base = (long long)B * UCAP + (long long)(wave - B) * ICAP; if (n > ICAP) n = ICAP; }
    } else {
        base = offs[wave];
        if (base + n > cap) n = (int)(cap - base < 0 ? 0 : cap - base);
    }

    int o = lane * 2;
    float ax = 0.f, ay = 0.f;
    for (int k0 = 0; k0 < n; k0 += 64) {
        int idx = k0 + lane;
        int2 e = make_int2(0, 0);
        if (idx < n) e = entries[base + idx];          // coalesced block prefetch
        int m = n - k0;
        if (m > 64) m = 64;
        int j = 0;
        for (; j + 4 <= m; j += 4) {
            int s0 = __shfl(e.x, j + 0), s1 = __shfl(e.x, j + 1);
            int s2 = __shfl(e.x, j + 2), s3 = __shfl(e.x, j + 3);
            float d0 = __int_as_float(__shfl(e.y, j + 0));
            float d1 = __int_as_float(__shfl(e.y, j + 1));
            float d2 = __int_as_float(__shfl(e.y, j + 2));
            float d3 = __int_as_float(__shfl(e.y, j + 3));
            float2 r0 = *(const float2*)(table + (size_t)s0 * DIM + o);
            float2 r1 = *(const float2*)(table + (size_t)s1 * DIM + o);
            float2 r2 = *(const float2*)(table + (size_t)s2 * DIM + o);
            float2 r3 = *(const float2*)(table + (size_t)s3 * DIM + o);
            ax += d0 * r0.x; ay += d0 * r0.y;
            ax += d1 * r1.x; ay += d1 * r1.y;
            ax += d2 * r2.x; ay += d2 * r2.y;
            ax += d3 * r3.x; ay += d3 * r3.y;
        }
        for (; j < m; j++) {
            int s = __shfl(e.x, j);
            float dv = __int_as_float(__shfl(e.y, j));
            float2 r = *(const float2*)(table + (size_t)s * DIM + o);
            ax += dv * r.x; ay += dv * r.y;
        }
    }
    *(float2*)(dst + o) = make_float2(ax, ay);
}

// ---------------------------------------------------------------------------
// G: scoring. One wave per batch element.
// ---------------------------------------------------------------------------
__global__ void score_kernel(const float* __restrict__ u0, const float* __restrict__ i0,
                             const float* __restrict__ u1c, const float* __restrict__ i1c,
                             const int* __restrict__ user, const int* __restrict__ pos,
                             const int* __restrict__ neg, const int* __restrict__ u_slot,
                             const int* __restrict__ i_slot, float* __restrict__ out, int B) {
    int wave = (blockIdx.x * blockDim.x + threadIdx.x) >> 6;
    int lane = threadIdx.x & 63;
    if (wave >= B) return;

    int ub = user[wave], pb = pos[wave], nb = neg[wave];
    int usl = u_slot[ub], psl = i_slot[pb], nsl = i_slot[nb];
    int o = lane * 2;

    float2 a0 = *(const float2*)(u0  + (size_t)ub  * DIM + o);
    float2 a1 = *(const float2*)(u1c + (size_t)usl * DIM + o);
    float2 p0 = *(const float2*)(i0  + (size_t)pb  * DIM + o);
    float2 p1 = *(const float2*)(i1c + (size_t)psl * DIM + o);
    float2 n0 = *(const float2*)(i0  + (size_t)nb  * DIM + o);
    float2 n1 = *(const float2*)(i1c + (size_t)nsl * DIM + o);

    float ux = (a0.x + a1.x) * 0.5f, uy = (a0.y + a1.y) * 0.5f;
    float px = (p0.x + p1.x) * 0.5f, py = (p0.y + p1.y) * 0.5f;
    float nx = (n0.x + n1.x) * 0.5f, ny = (n0.y + n1.y) * 0.5f;

    float ps = ux * px + uy * py;
    float ns = ux * nx + uy * ny;
    for (int off = 32; off > 0; off >>= 1) {
        ps += __shfl_down(ps, off);
        ns += __shfl_down(ns, off);
    }
    if (lane == 0) {
        out[wave]     = ps;
        out[B + wave] = ns;
    }
}

extern "C" void kernel_launch(void* const* d_in, const int* in_sizes, int n_in,
                              void* d_out, int out_size, void* d_ws, size_t ws_size,
                              hipStream_t stream) {
    const float* user_emb = (const float*)d_in[0];
    const float* item_emb = (const float*)d_in[1];
    const float* vals     = (const float*)d_in[2];
    const float* keep     = (const float*)d_in[3];
    const int*   rows     = (const int*)d_in[4];
    const int*   cols     = (const int*)d_in[5];
    const int*   user     = (const int*)d_in[6];
    const int*   pos      = (const int*)d_in[7];
    const int*   neg      = (const int*)d_in[8];
    float* out = (float*)d_out;

    int U = in_sizes[0] / DIM;   // 100000
    int I = in_sizes[1] / DIM;   // 50000
    int E = in_sizes[2];         // 3200000
    int B = in_sizes[6];         // 4096

    char* p = (char*)d_ws;
    int* u_slot = (int*)p;              p += (size_t)U * 4;
    int* i_slot = (int*)p;              p += (size_t)I * 4;
    int* cnt    = (int*)p;              p += (size_t)3 * B * 4;
    int* offs   = (int*)p;              p += (size_t)3 * B * 4;
    int* cursor = (int*)p;              p += (size_t)3 * B * 4;
    float* u1c  = (float*)p;            p += (size_t)B * DIM * 4;
    float* i1c  = (float*)p;            p += (size_t)2 * B * DIM * 4;
    int2* entries = (int2*)p;
    size_t used = (size_t)(p - (char*)d_ws);
    long long avail = (long long)ws_size - (long long)used;

    long long bucket_entries = (long long)B * UCAP + (long long)2 * B * ICAP;  // 1,703,936
    int mode = (avail >= bucket_entries * (long long)sizeof(int2)) ? 1 : 0;

    int slot_vecs = (U + I) / 4;        // exact
    int ctr_vecs  = (9 * B) / 4;        // cnt+offs+cursor contiguous, exact

    init_ws_kernel<<<256, 256, 0, stream>>>((int4*)u_slot, slot_vecs, (int4*)cnt, ctr_vecs);
    slot_kernel<<<(3 * B + 255) / 256, 256, 0, stream>>>(user, pos, neg, u_slot, i_slot, B);

    int scan_threads = (E + 3) / 4;
    int scan_blocks = (scan_threads + 255) / 256;

    long long cap;
    if (mode == 1) {
        cap = bucket_entries;
        fill_bucket_kernel<<<scan_blocks, 256, 0, stream>>>(vals, keep, rows, cols, u_slot,
                                                            i_slot, cursor, entries, E, B);
        // gather reads counts from cursor
        gather_kernel<<<(3 * B * 64 + 255) / 256, 256, 0, stream>>>(entries, offs, cursor,
                                                                    user_emb, item_emb, u1c,
                                                                    i1c, B, 1, cap);
    } else {
        cap = avail / (long long)sizeof(int2);
        if (cap < 0) cap = 0;
        count_kernel<<<scan_blocks, 256, 0, stream>>>(keep, rows, cols, u_slot, i_slot, cnt, E, B);
        scan_kernel<<<1, 1024, 0, stream>>>(cnt, offs, cursor, 3 * B);
        fill_csr_kernel<<<scan_blocks, 256, 0, stream>>>(vals, keep, rows, cols, u_slot, i_slot,
                                                         cursor, entries, cap, E, B);
        gather_kernel<<<(3 * B * 64 + 255) / 256, 256, 0, stream>>>(entries, offs, cnt,
                                                                    user_emb, item_emb, u1c,
                                                                    i1c, B, 0, cap);
    }

    score_kernel<<<(B * 64 + 255) / 256, 256, 0, stream>>>(user_emb, item_emb, u1c, i1c,
                                                           user, pos, neg, u_slot, i_slot,
                                                           out, B);
}

// Round 4
// 220.172 us; speedup vs baseline: 2.4334x; 1.0350x over previous
//
#include <hip/hip_runtime.h>

#define DIM 128
#define KEEP_PROB 0.8f
#define UCAP 96    // user-side bucket capacity  (kept-degree ~Poisson(25.6))
#define ICAP 160   // item-side bucket capacity  (kept-degree ~Poisson(51.2))

// ---------------------------------------------------------------------------
// B: scatter batch indices into slot maps + membership bitmasks.
// Dup indices: last writer wins on slots; every consumer re-reads the map, so
// all agree on the winning compact row. Masks: bit set iff index is in batch.
// ---------------------------------------------------------------------------
__global__ void slot_kernel(const int* __restrict__ user, const int* __restrict__ pos,
                            const int* __restrict__ neg, int* __restrict__ u_slot,
                            int* __restrict__ i_slot, unsigned* __restrict__ u_mask,
                            unsigned* __restrict__ i_mask, int B) {
    int t = blockIdx.x * blockDim.x + threadIdx.x;
    if (t < B) {
        int u = user[t];
        u_slot[u] = t;
        atomicOr(&u_mask[u >> 5], 1u << (u & 31));
    } else if (t < 2 * B) {
        int it = pos[t - B];
        i_slot[it] = t - B;
        atomicOr(&i_mask[it >> 5], 1u << (it & 31));
    } else if (t < 3 * B) {
        int it = neg[t - 2 * B];
        i_slot[it] = (t - 2 * B) + B;
        atomicOr(&i_mask[it >> 5], 1u << (it & 31));
    }
}

// ---------------------------------------------------------------------------
// C (bucket path): single-pass fill. Predicate via L1-resident bitmasks
// (18.8 KB total) -> slot lookup (L2) only on real hits (~490k of 6.4M).
// 8 edges/thread for load-level parallelism.
// ---------------------------------------------------------------------------
__global__ void fill_bucket_kernel(const float* __restrict__ vals, const float* __restrict__ keep,
                                   const int* __restrict__ rows, const int* __restrict__ cols,
                                   const int* __restrict__ u_slot, const int* __restrict__ i_slot,
                                   const unsigned* __restrict__ u_mask,
                                   const unsigned* __restrict__ i_mask,
                                   int* __restrict__ cursor, int2* __restrict__ entries,
                                   int E, int B) {
    int t = blockIdx.x * blockDim.x + threadIdx.x;
    int base = t * 8;
    if (base >= E) return;
    long long ib = (long long)B * UCAP;
    if (base + 7 < E) {
        float4 ka = *(const float4*)(keep + base), kb = *(const float4*)(keep + base + 4);
        float4 va = *(const float4*)(vals + base), vb = *(const float4*)(vals + base + 4);
        int4 ra = *(const int4*)(rows + base), rb = *(const int4*)(rows + base + 4);
        int4 ca = *(const int4*)(cols + base), cb = *(const int4*)(cols + base + 4);
        float kk[8] = {ka.x, ka.y, ka.z, ka.w, kb.x, kb.y, kb.z, kb.w};
        float vv[8] = {va.x, va.y, va.z, va.w, vb.x, vb.y, vb.z, vb.w};
        int rr[8] = {ra.x, ra.y, ra.z, ra.w, rb.x, rb.y, rb.z, rb.w};
        int cc[8] = {ca.x, ca.y, ca.z, ca.w, cb.x, cb.y, cb.z, cb.w};
#pragma unroll
        for (int j = 0; j < 8; j++) {
            if (kk[j] < KEEP_PROB) {
                int r = rr[j], c = cc[j];
                float dv = vv[j] * 1.25f;   // 1/0.8 exactly representable
                if ((u_mask[r >> 5] >> (r & 31)) & 1u) {
                    int us = u_slot[r];
                    int p = atomicAdd(&cursor[us], 1);
                    if (p < UCAP) entries[(long long)us * UCAP + p] = make_int2(c, __float_as_int(dv));
                }
                if ((i_mask[c >> 5] >> (c & 31)) & 1u) {
                    int is = i_slot[c];
                    int p = atomicAdd(&cursor[B + is], 1);
                    if (p < ICAP) entries[ib + (long long)is * ICAP + p] = make_int2(r, __float_as_int(dv));
                }
            }
        }
    } else {
        for (int e = base; e < E; e++) {
            if (keep[e] < KEEP_PROB) {
                int r = rows[e], c = cols[e];
                float dv = vals[e] * 1.25f;
                if ((u_mask[r >> 5] >> (r & 31)) & 1u) {
                    int us = u_slot[r];
                    int p = atomicAdd(&cursor[us], 1);
                    if (p < UCAP) entries[(long long)us * UCAP + p] = make_int2(c, __float_as_int(dv));
                }
                if ((i_mask[c >> 5] >> (c & 31)) & 1u) {
                    int is = i_slot[c];
                    int p = atomicAdd(&cursor[B + is], 1);
                    if (p < ICAP) entries[ib + (long long)is * ICAP + p] = make_int2(r, __float_as_int(dv));
                }
            }
        }
    }
}

// ---------------------------------------------------------------------------
// CSR fallback (only if ws too small for buckets): count -> scan -> fill.
// ---------------------------------------------------------------------------
__global__ void count_kernel(const float* __restrict__ keep, const int* __restrict__ rows,
                             const int* __restrict__ cols, const int* __restrict__ u_slot,
                             const int* __restrict__ i_slot, int* __restrict__ cnt,
                             int E, int B) {
    int t = blockIdx.x * blockDim.x + threadIdx.x;
    int base = t * 4;
    if (base >= E) return;
    for (int e = base; e < base + 4 && e < E; e++) {
        if (keep[e] < KEEP_PROB) {
            int us = u_slot[rows[e]];
            if (us >= 0) atomicAdd(&cnt[us], 1);
            int is = i_slot[cols[e]];
            if (is >= 0) atomicAdd(&cnt[B + is], 1);
        }
    }
}

__global__ void scan_kernel(const int* __restrict__ cnt, int* __restrict__ offs,
                            int* __restrict__ cursor, int n) {
    __shared__ int wave_tot[16];
    __shared__ int carry_s;
    int tid = threadIdx.x, lane = tid & 63, wv = tid >> 6;
    if (tid == 0) carry_s = 0;
    __syncthreads();
    for (int base = 0; base < n; base += 1024) {
        int v = (base + tid < n) ? cnt[base + tid] : 0;
        int x = v;
#pragma unroll
        for (int off = 1; off < 64; off <<= 1) {
            int y = __shfl_up(x, off);
            if (lane >= off) x += y;
        }
        if (lane == 63) wave_tot[wv] = x;
        __syncthreads();
        if (wv == 0 && lane < 16) {
            int tot = wave_tot[lane];
            int s = tot;
#pragma unroll
            for (int off = 1; off < 16; off <<= 1) {
                int y = __shfl_up(s, off);
                if (lane >= off) s += y;
            }
            wave_tot[lane] = s - tot;
        }
        __syncthreads();
        int excl = (x - v) + wave_tot[wv] + carry_s;
        if (base + tid < n) { offs[base + tid] = excl; cursor[base + tid] = excl; }
        __syncthreads();
        if (tid == 1023) carry_s += wave_tot[15] + x;
        __syncthreads();
    }
}

__global__ void fill_csr_kernel(const float* __restrict__ vals, const float* __restrict__ keep,
                                const int* __restrict__ rows, const int* __restrict__ cols,
                                const int* __restrict__ u_slot, const int* __restrict__ i_slot,
                                int* __restrict__ cursor, int2* __restrict__ entries,
                                long long cap, int E, int B) {
    int t = blockIdx.x * blockDim.x + threadIdx.x;
    int base = t * 4;
    if (base >= E) return;
    for (int e = base; e < base + 4 && e < E; e++) {
        if (keep[e] < KEEP_PROB) {
            float dv = vals[e] * 1.25f;
            int us = u_slot[rows[e]];
            if (us >= 0) {
                int p = atomicAdd(&cursor[us], 1);
                if (p < cap) entries[p] = make_int2(cols[e], __float_as_int(dv));
            }
            int is = i_slot[cols[e]];
            if (is >= 0) {
                int p = atomicAdd(&cursor[B + is], 1);
                if (p < cap) entries[p] = make_int2(rows[e], __float_as_int(dv));
            }
        }
    }
}

// ---------------------------------------------------------------------------
// F: gather. 2 waves per destination row (even/odd entry split, LDS combine).
// Block = 256 threads = 2 dest-pairs. Per wave: coalesced-ish strided entry
// prefetch (one per lane), shfl-broadcast, 8 independent 512B row gathers in
// flight. No atomics; single plain float2 store per dest.
// ---------------------------------------------------------------------------
__global__ void gather_kernel(const int2* __restrict__ entries, const int* __restrict__ offs,
                              const int* __restrict__ cntp, const float* __restrict__ u0,
                              const float* __restrict__ i0, float* __restrict__ u1c,
                              float* __restrict__ i1c, int B, int mode, long long cap) {
    __shared__ float part[2][DIM];
    int pair = threadIdx.x >> 7;          // which of 2 dests in this block
    int half = (threadIdx.x >> 6) & 1;    // which wave of the pair
    int lane = threadIdx.x & 63;
    int dest = blockIdx.x * 2 + pair;     // grid sized exactly: dest < 3B

    const float* table;
    float* dst;
    if (dest < B) { table = i0; dst = u1c + (size_t)dest * DIM; }
    else          { table = u0; dst = i1c + (size_t)(dest - B) * DIM; }

    int n = cntp[dest];
    long long base;
    if (mode == 1) {
        if (dest < B) { base = (long long)dest * UCAP; if (n > UCAP) n = UCAP; }
        else { base = (long long)B * UCAP + (long long)(dest - B) * ICAP; if (n > ICAP) n = ICAP; }
    } else {
        base = offs[dest];
        if (base + n > cap) { long long rem = cap - base; n = rem < 0 ? 0 : (int)rem; }
    }

    int m = (n - half + 1) >> 1;          // this wave's entries: half, half+2, ...
    int o = lane * 2;
    float ax = 0.f, ay = 0.f;
    for (int k0 = 0; k0 < m; k0 += 64) {
        int my = k0 + lane;
        int2 e = make_int2(0, 0);
        if (my < m) e = entries[base + half + 2 * (long long)my];
        int mm = m - k0;
        if (mm > 64) mm = 64;
        int j = 0;
        for (; j + 8 <= mm; j += 8) {
            int s0 = __shfl(e.x, j + 0), s1 = __shfl(e.x, j + 1);
            int s2 = __shfl(e.x, j + 2), s3 = __shfl(e.x, j + 3);
            int s4 = __shfl(e.x, j + 4), s5 = __shfl(e.x, j + 5);
            int s6 = __shfl(e.x, j + 6), s7 = __shfl(e.x, j + 7);
            float d0 = __int_as_float(__shfl(e.y, j + 0));
            float d1 = __int_as_float(__shfl(e.y, j + 1));
            float d2 = __int_as_float(__shfl(e.y, j + 2));
            float d3 = __int_as_float(__shfl(e.y, j + 3));
            float d4 = __int_as_float(__shfl(e.y, j + 4));
            float d5 = __int_as_float(__shfl(e.y, j + 5));
            float d6 = __int_as_float(__shfl(e.y, j + 6));
            float d7 = __int_as_float(__shfl(e.y, j + 7));
            float2 r0 = *(const float2*)(table + (size_t)s0 * DIM + o);
            float2 r1 = *(const float2*)(table + (size_t)s1 * DIM + o);
            float2 r2 = *(const float2*)(table + (size_t)s2 * DIM + o);
            float2 r3 = *(const float2*)(table + (size_t)s3 * DIM + o);
            float2 r4 = *(const float2*)(table + (size_t)s4 * DIM + o);
            float2 r5 = *(const float2*)(table + (size_t)s5 * DIM + o);
            float2 r6 = *(const float2*)(table + (size_t)s6 * DIM + o);
            float2 r7 = *(const float2*)(table + (size_t)s7 * DIM + o);
            ax += d0 * r0.x; ay += d0 * r0.y;
            ax += d1 * r1.x; ay += d1 * r1.y;
            ax += d2 * r2.x; ay += d2 * r2.y;
            ax += d3 * r3.x; ay += d3 * r3.y;
            ax += d4 * r4.x; ay += d4 * r4.y;
            ax += d5 * r5.x; ay += d5 * r5.y;
            ax += d6 * r6.x; ay += d6 * r6.y;
            ax += d7 * r7.x; ay += d7 * r7.y;
        }
        for (; j < mm; j++) {
            int s = __shfl(e.x, j);
            float dv = __int_as_float(__shfl(e.y, j));
            float2 r = *(const float2*)(table + (size_t)s * DIM + o);
            ax += dv * r.x; ay += dv * r.y;
        }
    }
    if (half == 1) { part[pair][o] = ax; part[pair][o + 1] = ay; }
    __syncthreads();
    if (half == 0) {
        ax += part[pair][o];
        ay += part[pair][o + 1];
        *(float2*)(dst + o) = make_float2(ax, ay);
    }
}

// ---------------------------------------------------------------------------
// G: scoring. One wave per batch element.
// ---------------------------------------------------------------------------
__global__ void score_kernel(const float* __restrict__ u0, const float* __restrict__ i0,
                             const float* __restrict__ u1c, const float* __restrict__ i1c,
                             const int* __restrict__ user, const int* __restrict__ pos,
                             const int* __restrict__ neg, const int* __restrict__ u_slot,
                             const int* __restrict__ i_slot, float* __restrict__ out, int B) {
    int wave = (blockIdx.x * blockDim.x + threadIdx.x) >> 6;
    int lane = threadIdx.x & 63;
    if (wave >= B) return;

    int ub = user[wave], pb = pos[wave], nb = neg[wave];
    int usl = u_slot[ub], psl = i_slot[pb], nsl = i_slot[nb];
    int o = lane * 2;

    float2 a0 = *(const float2*)(u0  + (size_t)ub  * DIM + o);
    float2 a1 = *(const float2*)(u1c + (size_t)usl * DIM + o);
    float2 p0 = *(const float2*)(i0  + (size_t)pb  * DIM + o);
    float2 p1 = *(const float2*)(i1c + (size_t)psl * DIM + o);
    float2 n0 = *(const float2*)(i0  + (size_t)nb  * DIM + o);
    float2 n1 = *(const float2*)(i1c + (size_t)nsl * DIM + o);

    float ux = (a0.x + a1.x) * 0.5f, uy = (a0.y + a1.y) * 0.5f;
    float px = (p0.x + p1.x) * 0.5f, py = (p0.y + p1.y) * 0.5f;
    float nx = (n0.x + n1.x) * 0.5f, ny = (n0.y + n1.y) * 0.5f;

    float ps = ux * px + uy * py;
    float ns = ux * nx + uy * ny;
    for (int off = 32; off > 0; off >>= 1) {
        ps += __shfl_down(ps, off);
        ns += __shfl_down(ns, off);
    }
    if (lane == 0) {
        out[wave]     = ps;
        out[B + wave] = ns;
    }
}

extern "C" void kernel_launch(void* const* d_in, const int* in_sizes, int n_in,
                              void* d_out, int out_size, void* d_ws, size_t ws_size,
                              hipStream_t stream) {
    const float* user_emb = (const float*)d_in[0];
    const float* item_emb = (const float*)d_in[1];
    const float* vals     = (const float*)d_in[2];
    const float* keep     = (const float*)d_in[3];
    const int*   rows     = (const int*)d_in[4];
    const int*   cols     = (const int*)d_in[5];
    const int*   user     = (const int*)d_in[6];
    const int*   pos      = (const int*)d_in[7];
    const int*   neg      = (const int*)d_in[8];
    float* out = (float*)d_out;

    int U = in_sizes[0] / DIM;   // 100000
    int I = in_sizes[1] / DIM;   // 50000
    int E = in_sizes[2];         // 3200000
    int B = in_sizes[6];         // 4096

    int umw = ((U + 31) / 32 + 3) & ~3;   // mask words, 16B-multiple
    int imw = ((I + 31) / 32 + 3) & ~3;

    char* p = (char*)d_ws;
    int* u_slot = (int*)p;              p += (size_t)U * 4;
    int* i_slot = (int*)p;              p += (size_t)I * 4;
    unsigned* u_mask = (unsigned*)p;    p += (size_t)umw * 4;
    unsigned* i_mask = (unsigned*)p;    p += (size_t)imw * 4;
    int* cnt    = (int*)p;              p += (size_t)3 * B * 4;
    int* offs   = (int*)p;              p += (size_t)3 * B * 4;
    int* cursor = (int*)p;              p += (size_t)3 * B * 4;
    float* u1c  = (float*)p;            p += (size_t)B * DIM * 4;
    float* i1c  = (float*)p;            p += (size_t)2 * B * DIM * 4;
    int2* entries = (int2*)p;
    size_t used = (size_t)(p - (char*)d_ws);
    long long avail = (long long)ws_size - (long long)used;

    long long bucket_entries = (long long)B * UCAP + (long long)2 * B * ICAP;  // 1,703,936
    int mode = (avail >= bucket_entries * (long long)sizeof(int2)) ? 1 : 0;

    // Init: slots <- -1 (0xFF pattern), masks+cnt+offs+cursor <- 0. DMA, no kernel.
    hipMemsetAsync(u_slot, 0xFF, (size_t)(U + I) * 4, stream);
    hipMemsetAsync(u_mask, 0x00, (size_t)(umw + imw + 9 * B) * 4, stream);

    slot_kernel<<<(3 * B + 255) / 256, 256, 0, stream>>>(user, pos, neg, u_slot, i_slot,
                                                         u_mask, i_mask, B);

    long long cap;
    if (mode == 1) {
        cap = bucket_entries;
        int fb = ((E + 7) / 8 + 255) / 256;
        fill_bucket_kernel<<<fb, 256, 0, stream>>>(vals, keep, rows, cols, u_slot, i_slot,
                                                   u_mask, i_mask, cursor, entries, E, B);
        gather_kernel<<<(3 * B) / 2, 256, 0, stream>>>(entries, offs, cursor, user_emb,
                                                       item_emb, u1c, i1c, B, 1, cap);
    } else {
        cap = avail / (long long)sizeof(int2);
        if (cap < 0) cap = 0;
        int cb = ((E + 3) / 4 + 255) / 256;
        count_kernel<<<cb, 256, 0, stream>>>(keep, rows, cols, u_slot, i_slot, cnt, E, B);
        scan_kernel<<<1, 1024, 0, stream>>>(cnt, offs, cursor, 3 * B);
        fill_csr_kernel<<<cb, 256, 0, stream>>>(vals, keep, rows, cols, u_slot, i_slot,
                                                cursor, entries, cap, E, B);
        gather_kernel<<<(3 * B) / 2, 256, 0, stream>>>(entries, offs, cnt, user_emb,
                                                       item_emb, u1c, i1c, B, 0, cap);
    }

    score_kernel<<<(B * 64 + 255) / 256, 256, 0, stream>>>(user_emb, item_emb, u1c, i1c,
                                                           user, pos, neg, u_slot, i_slot,
                                                           out, B);
}

// Round 5
// 219.644 us; speedup vs baseline: 2.4392x; 1.0024x over previous
//
#include <hip/hip_runtime.h>

#define DIM 128
#define KEEP_PROB 0.8f
#define UCAP 96    // user-side bucket capacity  (kept-degree ~Poisson(25.6), max~49)
#define ICAP 160   // item-side bucket capacity  (kept-degree ~Poisson(51.2), max~80)
#define SMASK_WORDS 5120   // LDS budget for bitmasks (20 KB; need 4689 for U=100k,I=50k)

// ---------------------------------------------------------------------------
// B: scatter batch indices into slot maps + membership bitmasks.
// Dup indices: last writer wins on slots; every consumer re-reads the map, so
// all agree on the winning compact row. Mask bit set iff index is in batch;
// slot[x] is only ever read where mask(x)=1, so slots need NO init.
// ---------------------------------------------------------------------------
__global__ void slot_kernel(const int* __restrict__ user, const int* __restrict__ pos,
                            const int* __restrict__ neg, int* __restrict__ u_slot,
                            int* __restrict__ i_slot, unsigned* __restrict__ u_mask,
                            unsigned* __restrict__ i_mask, int B) {
    int t = blockIdx.x * blockDim.x + threadIdx.x;
    if (t < B) {
        int u = user[t];
        u_slot[u] = t;
        atomicOr(&u_mask[u >> 5], 1u << (u & 31));
    } else if (t < 2 * B) {
        int it = pos[t - B];
        i_slot[it] = t - B;
        atomicOr(&i_mask[it >> 5], 1u << (it & 31));
    } else if (t < 3 * B) {
        int it = neg[t - 2 * B];
        i_slot[it] = (t - 2 * B) + B;
        atomicOr(&i_mask[it >> 5], 1u << (it & 31));
    }
}

// ---------------------------------------------------------------------------
// C (bucket path): single-pass fill. Membership test via LDS-resident
// bitmasks (immune to the L1 thrash from the 51 MB metadata stream).
// Scattered global traffic only on real hits (~500k of 6.4M candidates).
// ---------------------------------------------------------------------------
template <bool LDS>
__global__ void fill_bucket_kernel(const float* __restrict__ vals, const float* __restrict__ keep,
                                   const int* __restrict__ rows, const int* __restrict__ cols,
                                   const int* __restrict__ u_slot, const int* __restrict__ i_slot,
                                   const unsigned* __restrict__ masks, int umw, int mw_total,
                                   int* __restrict__ cursor, int2* __restrict__ entries,
                                   int E, int B) {
    __shared__ unsigned sm[LDS ? SMASK_WORDS : 1];
    const unsigned *um, *im;
    if constexpr (LDS) {
        for (int i = threadIdx.x; i < mw_total; i += blockDim.x) sm[i] = masks[i];
        __syncthreads();
        um = sm; im = sm + umw;
    } else {
        um = masks; im = masks + umw;
    }

    int t = blockIdx.x * blockDim.x + threadIdx.x;
    int base = t * 8;
    if (base >= E) return;
    long long ib = (long long)B * UCAP;
    if (base + 7 < E) {
        float4 ka = *(const float4*)(keep + base), kb = *(const float4*)(keep + base + 4);
        float4 va = *(const float4*)(vals + base), vb = *(const float4*)(vals + base + 4);
        int4 ra = *(const int4*)(rows + base), rb = *(const int4*)(rows + base + 4);
        int4 ca = *(const int4*)(cols + base), cb = *(const int4*)(cols + base + 4);
        float kk[8] = {ka.x, ka.y, ka.z, ka.w, kb.x, kb.y, kb.z, kb.w};
        float vv[8] = {va.x, va.y, va.z, va.w, vb.x, vb.y, vb.z, vb.w};
        int rr[8] = {ra.x, ra.y, ra.z, ra.w, rb.x, rb.y, rb.z, rb.w};
        int cc[8] = {ca.x, ca.y, ca.z, ca.w, cb.x, cb.y, cb.z, cb.w};
#pragma unroll
        for (int j = 0; j < 8; j++) {
            if (kk[j] < KEEP_PROB) {
                int r = rr[j], c = cc[j];
                float dv = vv[j] * 1.25f;   // 1/0.8 exactly representable
                if ((um[r >> 5] >> (r & 31)) & 1u) {
                    int us = u_slot[r];
                    int p = atomicAdd(&cursor[us], 1);
                    if (p < UCAP) entries[(long long)us * UCAP + p] = make_int2(c, __float_as_int(dv));
                }
                if ((im[c >> 5] >> (c & 31)) & 1u) {
                    int is = i_slot[c];
                    int p = atomicAdd(&cursor[B + is], 1);
                    if (p < ICAP) entries[ib + (long long)is * ICAP + p] = make_int2(r, __float_as_int(dv));
                }
            }
        }
    } else {
        for (int e = base; e < E; e++) {
            if (keep[e] < KEEP_PROB) {
                int r = rows[e], c = cols[e];
                float dv = vals[e] * 1.25f;
                if ((um[r >> 5] >> (r & 31)) & 1u) {
                    int us = u_slot[r];
                    int p = atomicAdd(&cursor[us], 1);
                    if (p < UCAP) entries[(long long)us * UCAP + p] = make_int2(c, __float_as_int(dv));
                }
                if ((im[c >> 5] >> (c & 31)) & 1u) {
                    int is = i_slot[c];
                    int p = atomicAdd(&cursor[B + is], 1);
                    if (p < ICAP) entries[ib + (long long)is * ICAP + p] = make_int2(r, __float_as_int(dv));
                }
            }
        }
    }
}

// ---------------------------------------------------------------------------
// CSR fallback (only if ws too small for buckets): count -> scan -> fill.
// Uses slot>=0 predicate, so this path memsets the slot tables to -1.
// ---------------------------------------------------------------------------
__global__ void count_kernel(const float* __restrict__ keep, const int* __restrict__ rows,
                             const int* __restrict__ cols, const int* __restrict__ u_slot,
                             const int* __restrict__ i_slot, int* __restrict__ cnt,
                             int E, int B) {
    int t = blockIdx.x * blockDim.x + threadIdx.x;
    int base = t * 4;
    if (base >= E) return;
    for (int e = base; e < base + 4 && e < E; e++) {
        if (keep[e] < KEEP_PROB) {
            int us = u_slot[rows[e]];
            if (us >= 0) atomicAdd(&cnt[us], 1);
            int is = i_slot[cols[e]];
            if (is >= 0) atomicAdd(&cnt[B + is], 1);
        }
    }
}

__global__ void scan_kernel(const int* __restrict__ cnt, int* __restrict__ offs,
                            int* __restrict__ cursor, int n) {
    __shared__ int wave_tot[16];
    __shared__ int carry_s;
    int tid = threadIdx.x, lane = tid & 63, wv = tid >> 6;
    if (tid == 0) carry_s = 0;
    __syncthreads();
    for (int base = 0; base < n; base += 1024) {
        int v = (base + tid < n) ? cnt[base + tid] : 0;
        int x = v;
#pragma unroll
        for (int off = 1; off < 64; off <<= 1) {
            int y = __shfl_up(x, off);
            if (lane >= off) x += y;
        }
        if (lane == 63) wave_tot[wv] = x;
        __syncthreads();
        if (wv == 0 && lane < 16) {
            int tot = wave_tot[lane];
            int s = tot;
#pragma unroll
            for (int off = 1; off < 16; off <<= 1) {
                int y = __shfl_up(s, off);
                if (lane >= off) s += y;
            }
            wave_tot[lane] = s - tot;
        }
        __syncthreads();
        int excl = (x - v) + wave_tot[wv] + carry_s;
        if (base + tid < n) { offs[base + tid] = excl; cursor[base + tid] = excl; }
        __syncthreads();
        if (tid == 1023) carry_s += wave_tot[15] + x;
        __syncthreads();
    }
}

__global__ void fill_csr_kernel(const float* __restrict__ vals, const float* __restrict__ keep,
                                const int* __restrict__ rows, const int* __restrict__ cols,
                                const int* __restrict__ u_slot, const int* __restrict__ i_slot,
                                int* __restrict__ cursor, int2* __restrict__ entries,
                                long long cap, int E, int B) {
    int t = blockIdx.x * blockDim.x + threadIdx.x;
    int base = t * 4;
    if (base >= E) return;
    for (int e = base; e < base + 4 && e < E; e++) {
        if (keep[e] < KEEP_PROB) {
            float dv = vals[e] * 1.25f;
            int us = u_slot[rows[e]];
            if (us >= 0) {
                int p = atomicAdd(&cursor[us], 1);
                if (p < cap) entries[p] = make_int2(cols[e], __float_as_int(dv));
            }
            int is = i_slot[cols[e]];
            if (is >= 0) {
                int p = atomicAdd(&cursor[B + is], 1);
                if (p < cap) entries[p] = make_int2(rows[e], __float_as_int(dv));
            }
        }
    }
}

// ---------------------------------------------------------------------------
// F: gather. One block (4 waves) per destination row; wave w takes entries
// w, w+4, w+8, ... (per-wave serial chain ~6-12 entries), batches of 4
// independent 512B row gathers, LDS combine of partials. No atomics.
// ---------------------------------------------------------------------------
__global__ void gather_kernel(const int2* __restrict__ entries, const int* __restrict__ offs,
                              const int* __restrict__ cntp, const float* __restrict__ u0,
                              const float* __restrict__ i0, float* __restrict__ u1c,
                              float* __restrict__ i1c, int B, int mode, long long cap) {
    __shared__ float part[3][DIM];
    int wv = threadIdx.x >> 6;
    int lane = threadIdx.x & 63;
    int dest = blockIdx.x;                 // grid = 3B exactly

    const float* table;
    float* dst;
    if (dest < B) { table = i0; dst = u1c + (size_t)dest * DIM; }
    else          { table = u0; dst = i1c + (size_t)(dest - B) * DIM; }

    int n = cntp[dest];
    long long base;
    if (mode == 1) {
        if (dest < B) { base = (long long)dest * UCAP; if (n > UCAP) n = UCAP; }
        else { base = (long long)B * UCAP + (long long)(dest - B) * ICAP; if (n > ICAP) n = ICAP; }
    } else {
        base = offs[dest];
        if (base + (long long)n > cap) { long long rem = cap - base; n = rem < 0 ? 0 : (int)rem; }
    }

    int m = (n - wv + 3) >> 2;            // this wave's entry count (>=0)
    if (m < 0) m = 0;
    int o = lane * 2;
    float ax = 0.f, ay = 0.f;
    for (int k0 = 0; k0 < m; k0 += 64) {
        int my = k0 + lane;
        int2 e = make_int2(0, 0);
        if (my < m) e = entries[base + wv + 4 * (long long)my];
        int mm = m - k0;
        if (mm > 64) mm = 64;
        int j = 0;
        for (; j + 4 <= mm; j += 4) {
            int s0 = __shfl(e.x, j + 0), s1 = __shfl(e.x, j + 1);
            int s2 = __shfl(e.x, j + 2), s3 = __shfl(e.x, j + 3);
            float d0 = __int_as_float(__shfl(e.y, j + 0));
            float d1 = __int_as_float(__shfl(e.y, j + 1));
            float d2 = __int_as_float(__shfl(e.y, j + 2));
            float d3 = __int_as_float(__shfl(e.y, j + 3));
            float2 r0 = *(const float2*)(table + (size_t)s0 * DIM + o);
            float2 r1 = *(const float2*)(table + (size_t)s1 * DIM + o);
            float2 r2 = *(const float2*)(table + (size_t)s2 * DIM + o);
            float2 r3 = *(const float2*)(table + (size_t)s3 * DIM + o);
            ax += d0 * r0.x; ay += d0 * r0.y;
            ax += d1 * r1.x; ay += d1 * r1.y;
            ax += d2 * r2.x; ay += d2 * r2.y;
            ax += d3 * r3.x; ay += d3 * r3.y;
        }
        for (; j < mm; j++) {
            int s = __shfl(e.x, j);
            float dv = __int_as_float(__shfl(e.y, j));
            float2 r = *(const float2*)(table + (size_t)s * DIM + o);
            ax += dv * r.x; ay += dv * r.y;
        }
    }
    if (wv > 0) { part[wv - 1][o] = ax; part[wv - 1][o + 1] = ay; }
    __syncthreads();
    if (wv == 0) {
        ax += part[0][o] + part[1][o] + part[2][o];
        ay += part[0][o + 1] + part[1][o + 1] + part[2][o + 1];
        *(float2*)(dst + o) = make_float2(ax, ay);
    }
}

// ---------------------------------------------------------------------------
// G: scoring. One wave per batch element. (Slots valid: mask-covered.)
// ---------------------------------------------------------------------------
__global__ void score_kernel(const float* __restrict__ u0, const float* __restrict__ i0,
                             const float* __restrict__ u1c, const float* __restrict__ i1c,
                             const int* __restrict__ user, const int* __restrict__ pos,
                             const int* __restrict__ neg, const int* __restrict__ u_slot,
                             const int* __restrict__ i_slot, float* __restrict__ out, int B) {
    int wave = (blockIdx.x * blockDim.x + threadIdx.x) >> 6;
    int lane = threadIdx.x & 63;
    if (wave >= B) return;

    int ub = user[wave], pb = pos[wave], nb = neg[wave];
    int usl = u_slot[ub], psl = i_slot[pb], nsl = i_slot[nb];
    int o = lane * 2;

    float2 a0 = *(const float2*)(u0  + (size_t)ub  * DIM + o);
    float2 a1 = *(const float2*)(u1c + (size_t)usl * DIM + o);
    float2 p0 = *(const float2*)(i0  + (size_t)pb  * DIM + o);
    float2 p1 = *(const float2*)(i1c + (size_t)psl * DIM + o);
    float2 n0 = *(const float2*)(i0  + (size_t)nb  * DIM + o);
    float2 n1 = *(const float2*)(i1c + (size_t)nsl * DIM + o);

    float ux = (a0.x + a1.x) * 0.5f, uy = (a0.y + a1.y) * 0.5f;
    float px = (p0.x + p1.x) * 0.5f, py = (p0.y + p1.y) * 0.5f;
    float nx = (n0.x + n1.x) * 0.5f, ny = (n0.y + n1.y) * 0.5f;

    float ps = ux * px + uy * py;
    float ns = ux * nx + uy * ny;
    for (int off = 32; off > 0; off >>= 1) {
        ps += __shfl_down(ps, off);
        ns += __shfl_down(ns, off);
    }
    if (lane == 0) {
        out[wave]     = ps;
        out[B + wave] = ns;
    }
}

extern "C" void kernel_launch(void* const* d_in, const int* in_sizes, int n_in,
                              void* d_out, int out_size, void* d_ws, size_t ws_size,
                              hipStream_t stream) {
    const float* user_emb = (const float*)d_in[0];
    const float* item_emb = (const float*)d_in[1];
    const float* vals     = (const float*)d_in[2];
    const float* keep     = (const float*)d_in[3];
    const int*   rows     = (const int*)d_in[4];
    const int*   cols     = (const int*)d_in[5];
    const int*   user     = (const int*)d_in[6];
    const int*   pos      = (const int*)d_in[7];
    const int*   neg      = (const int*)d_in[8];
    float* out = (float*)d_out;

    int U = in_sizes[0] / DIM;   // 100000
    int I = in_sizes[1] / DIM;   // 50000
    int E = in_sizes[2];         // 3200000
    int B = in_sizes[6];         // 4096

    int umw = ((U + 31) / 32 + 3) & ~3;   // mask words, 16B-multiple
    int imw = ((I + 31) / 32 + 3) & ~3;

    char* p = (char*)d_ws;
    int* u_slot = (int*)p;              p += (size_t)U * 4;
    int* i_slot = (int*)p;              p += (size_t)I * 4;
    unsigned* u_mask = (unsigned*)p;    p += (size_t)umw * 4;
    unsigned* i_mask = (unsigned*)p;    p += (size_t)imw * 4;
    int* cnt    = (int*)p;              p += (size_t)3 * B * 4;
    int* offs   = (int*)p;              p += (size_t)3 * B * 4;
    int* cursor = (int*)p;              p += (size_t)3 * B * 4;
    float* u1c  = (float*)p;            p += (size_t)B * DIM * 4;
    float* i1c  = (float*)p;            p += (size_t)2 * B * DIM * 4;
    int2* entries = (int2*)p;
    size_t used = (size_t)(p - (char*)d_ws);
    long long avail = (long long)ws_size - (long long)used;

    long long bucket_entries = (long long)B * UCAP + (long long)2 * B * ICAP;  // 1,703,936
    int mode = (avail >= bucket_entries * (long long)sizeof(int2)) ? 1 : 0;

    // Zero masks + cnt/offs/cursor (contiguous). Slots need NO init in bucket
    // mode (mask-gated); CSR mode uses slot>=0 predicate, so init there.
    hipMemsetAsync(u_mask, 0x00, (size_t)(umw + imw + 9 * B) * 4, stream);
    if (mode == 0) hipMemsetAsync(u_slot, 0xFF, (size_t)(U + I) * 4, stream);

    slot_kernel<<<(3 * B + 255) / 256, 256, 0, stream>>>(user, pos, neg, u_slot, i_slot,
                                                         u_mask, i_mask, B);

    long long cap;
    if (mode == 1) {
        cap = bucket_entries;
        int fb = ((E + 7) / 8 + 255) / 256;
        if (umw + imw <= SMASK_WORDS) {
            fill_bucket_kernel<true><<<fb, 256, 0, stream>>>(vals, keep, rows, cols, u_slot,
                                                             i_slot, u_mask, umw, umw + imw,
                                                             cursor, entries, E, B);
        } else {
            fill_bucket_kernel<false><<<fb, 256, 0, stream>>>(vals, keep, rows, cols, u_slot,
                                                              i_slot, u_mask, umw, umw + imw,
                                                              cursor, entries, E, B);
        }
        gather_kernel<<<3 * B, 256, 0, stream>>>(entries, offs, cursor, user_emb, item_emb,
                                                 u1c, i1c, B, 1, cap);
    } else {
        cap = avail / (long long)sizeof(int2);
        if (cap < 0) cap = 0;
        int cb = ((E + 3) / 4 + 255) / 256;
        count_kernel<<<cb, 256, 0, stream>>>(keep, rows, cols, u_slot, i_slot, cnt, E, B);
        scan_kernel<<<1, 1024, 0, stream>>>(cnt, offs, cursor, 3 * B);
        fill_csr_kernel<<<cb, 256, 0, stream>>>(vals, keep, rows, cols, u_slot, i_slot,
                                                cursor, entries, cap, E, B);
        gather_kernel<<<3 * B, 256, 0, stream>>>(entries, offs, cnt, user_emb, item_emb,
                                                 u1c, i1c, B, 0, cap);
    }

    score_kernel<<<(B * 64 + 255) / 256, 256, 0, stream>>>(user_emb, item_emb, u1c, i1c,
                                                           user, pos, neg, u_slot, i_slot,
                                                           out, B);
}